// Round 6
// baseline (590.346 us; speedup 1.0000x reference)
//
#include <hip/hip_runtime.h>
#include <hip/hip_bf16.h>
#include <cstdint>
#include <cstddef>

// Problem constants
#define NTOK 8192   // N
#define NHID 1024   // hidden == n_spins

typedef __attribute__((ext_vector_type(8))) __bf16 bf16x8;
typedef __attribute__((ext_vector_type(4))) float f32x4;

__device__ __forceinline__ unsigned short f2bf(float f) {
    union { float f; unsigned u; } v; v.f = f;
    unsigned r = v.u + 0x7FFF + ((v.u >> 16) & 1);   // RNE
    return (unsigned short)(r >> 16);
}

__device__ __forceinline__ float bf2f(unsigned short u) {
    union { unsigned u; float f; } v; v.u = ((unsigned)u) << 16;
    return v.f;
}

__device__ __forceinline__ void async_copy16(const void* gsrc, void* ldsdst) {
    __builtin_amdgcn_global_load_lds(
        (const __attribute__((address_space(1))) unsigned int*)gsrc,
        (__attribute__((address_space(3))) unsigned int*)ldsdst,
        16, 0, 0);
}

// ---------------------------------------------------------------------------
// C[M,N] = epilogue( scale * (A[M,K] @ B[N,K]^T) + bias )  (A,B bf16)
// A row stride = lda, B row stride = ldb, C row stride = N (all elements).
// EPI 0: fp32, linear (plain store if SPLITK==1, atomicAdd if SPLITK>1)
// EPI 1: bf16 store, linear
// EPI 2: bf16 store, exp(scale*acc - 64) + fused column-sum atomicAdd to zsum
// SWAP: bm from blockIdx.x (row-blocks dispatch-fastest) — L3 locality for
//       tall-skinny C where A is the big re-read operand (attn@v).
// SPLITK: blockIdx.z covers K/SPLITK; raises resident blocks/CU for
//       small-grid GEMMs (attn@v grid was 512 = 2.0/CU, the R5 limiter).
// m97 structure: 128x128 tile, BK=64, 256 thr (4 waves, each 64x64),
// global_load_lds width=16 staging, mfma_f32_16x16x32_bf16.
// LDS bank-conflict fix: XOR swizzle chunk' = chunk ^ (row&7) within each
// 128-B LDS row, applied on the global-source side of staging and mirrored
// in the ds_read fragment addressing (R4: conflicts 5.03e7 -> 0).
// M,N multiples of 128; K multiple of 64*SPLITK.
// ---------------------------------------------------------------------------
template <int EPI, bool SWAP, int SPLITK>
__global__ __launch_bounds__(256) void gemm_bt(
    const unsigned short* __restrict__ A,
    const unsigned short* __restrict__ B,
    void* __restrict__ C,
    const float* __restrict__ bias,
    float* __restrict__ zsum,
    float scale, int M, int N, int K, int lda, int ldb)
{
    __shared__ __attribute__((aligned(16))) unsigned short As[128 * 64];
    __shared__ __attribute__((aligned(16))) unsigned short Bs[128 * 64];

    const int tid  = threadIdx.x;
    const int wave = tid >> 6;
    const int lane = tid & 63;
    const int bm = (SWAP ? blockIdx.x : blockIdx.y) * 128;
    const int bn = (SWAP ? blockIdx.y : blockIdx.x) * 128;
    const int Kloc = K / SPLITK;
    const int kz0 = (SPLITK > 1) ? blockIdx.z * Kloc : 0;
    const size_t ldaz = (size_t)lda;
    const size_t ldbz = (size_t)ldb;

    // staging: per wave, 4 issues of 16B/lane for A and B each.
    // LDS layout [row][k], 64 bf16 per row (128B), chunk XOR-swizzled by row&7.
    const int srow = lane >> 3;                        // 0..7 == row&7
    const int scol = ((lane & 7) ^ srow) * 8;          // swizzled k-chunk
    const unsigned short* Ag[4];
    const unsigned short* Bg[4];
    unsigned short* Al[4];
    unsigned short* Bl[4];
#pragma unroll
    for (int t = 0; t < 4; ++t) {
        int r = (wave * 4 + t) * 8 + srow;
        Ag[t] = A + (size_t)(bm + r) * ldaz + kz0 + scol;
        Bg[t] = B + (size_t)(bn + r) * ldbz + kz0 + scol;
        Al[t] = &As[(wave * 4 + t) * 512];   // wave-uniform base; HW adds lane*16B
        Bl[t] = &Bs[(wave * 4 + t) * 512];
    }

    const int wm = (wave >> 1) * 64;
    const int wn = (wave & 1) * 64;
    const int fr = lane & 15;          // fragment row (m or n)
    const int frl = fr & 7;            // row&7 for swizzle
    const int q = lane >> 4;           // quad index 0..3

    f32x4 acc[4][4] = {};

    for (int kt = 0; kt < Kloc; kt += 64) {
#pragma unroll
        for (int t = 0; t < 4; ++t) {
            async_copy16(Ag[t], Al[t]);
            async_copy16(Bg[t], Bl[t]);
            Ag[t] += 64;
            Bg[t] += 64;
        }
        __syncthreads();   // drains vmcnt for global_load_lds + barrier
#pragma unroll
        for (int ks = 0; ks < 2; ++ks) {
            const int pc = ((ks * 4 + q) ^ frl) * 8;   // swizzled chunk offset
            bf16x8 a[4], b[4];
#pragma unroll
            for (int i = 0; i < 4; ++i) {
                a[i] = *(const bf16x8*)&As[(wm + i * 16 + fr) * 64 + pc];
                b[i] = *(const bf16x8*)&Bs[(wn + i * 16 + fr) * 64 + pc];
            }
#pragma unroll
            for (int i = 0; i < 4; ++i)
#pragma unroll
                for (int j = 0; j < 4; ++j)
                    acc[i][j] = __builtin_amdgcn_mfma_f32_16x16x32_bf16(
                        a[i], b[j], acc[i][j], 0, 0, 0);
        }
        __syncthreads();
    }

    // epilogue: D[row=(lane>>4)*4+r][col=lane&15] per 16x16 tile (verified map)
    const int erow = q * 4;
#pragma unroll
    for (int j = 0; j < 4; ++j) {
        const int gcol = bn + wn + j * 16 + fr;
        const float bv = (EPI != 2 && bias) ? bias[gcol] : 0.0f;
        float colsum = 0.0f;
#pragma unroll
        for (int i = 0; i < 4; ++i) {
            const int grow0 = bm + wm + i * 16 + erow;
#pragma unroll
            for (int r = 0; r < 4; ++r) {
                float v;
                if (EPI == 2) {
                    // P = exp(scale*acc - 64): fixed-shift softmax numerator.
                    // scores ~ N(0,8^2), max ~48 << 64+87 (bf16 floor), so no
                    // overflow and column-relevant terms never underflow.
                    v = __expf(fmaf(acc[i][j][r], scale, -64.0f));
                    colsum += v;
                } else {
                    v = acc[i][j][r] * scale + bv;
                }
                size_t idx = (size_t)(grow0 + r) * N + gcol;
                if (EPI == 0) {
                    if (SPLITK > 1) atomicAdd(&((float*)C)[idx], v);
                    else            ((float*)C)[idx] = v;
                } else {
                    ((unsigned short*)C)[idx] = f2bf(v);
                }
            }
        }
        if (EPI == 2) {
            // reduce over the 4 quad-lanes holding this column (lane ^16, ^32)
            colsum += __shfl_xor(colsum, 16, 64);
            colsum += __shfl_xor(colsum, 32, 64);
            if (q == 0) atomicAdd(&zsum[gcol], colsum);
        }
    }
}

// fp32 -> bf16 elementwise, vectorized x4
__global__ void cvt_f32_bf16(const float4* __restrict__ src,
                             ushort4* __restrict__ dst, int n4)
{
    int i = blockIdx.x * blockDim.x + threadIdx.x;
    if (i < n4) {
        float4 f = src[i];
        ushort4 o;
        o.x = f2bf(f.x); o.y = f2bf(f.y); o.z = f2bf(f.z); o.w = f2bf(f.w);
        dst[i] = o;
    }
}

// v^T[h][j] *= 1/z_j   (in place on bf16 vtb, 8 j's per thread)
__global__ void vt_scale(uint4* __restrict__ vt8,
                         const float* __restrict__ z)
{
    int idx = blockIdx.x * blockDim.x + threadIdx.x;  // 0 .. H*N/8-1
    int jj = (idx & (NTOK / 8 - 1)) * 8;
    uint4 v = vt8[idx];
    unsigned short* vp = (unsigned short*)&v;
    float4 z0 = *(const float4*)&z[jj];
    float4 z1 = *(const float4*)&z[jj + 4];
    uint4 o;
    unsigned short* op = (unsigned short*)&o;
    op[0] = f2bf(bf2f(vp[0]) / z0.x);
    op[1] = f2bf(bf2f(vp[1]) / z0.y);
    op[2] = f2bf(bf2f(vp[2]) / z0.z);
    op[3] = f2bf(bf2f(vp[3]) / z0.w);
    op[4] = f2bf(bf2f(vp[4]) / z1.x);
    op[5] = f2bf(bf2f(vp[5]) / z1.y);
    op[6] = f2bf(bf2f(vp[6]) / z1.z);
    op[7] = f2bf(bf2f(vp[7]) / z1.w);
    vt8[idx] = o;
}

// d_out[row] = sum_h logcosh(out[row,h]); one block (256 thr) per row
__global__ void logcosh_rowsum(const float4* __restrict__ O4,
                               float* __restrict__ out)
{
    const float LN2 = 0.69314718055994531f;
    int row = blockIdx.x;
    float4 v = O4[(size_t)row * 256 + threadIdx.x];
    float s = 0.0f, a;
    a = fabsf(v.x); s += a + log1pf(__expf(-2.0f * a));
    a = fabsf(v.y); s += a + log1pf(__expf(-2.0f * a));
    a = fabsf(v.z); s += a + log1pf(__expf(-2.0f * a));
    a = fabsf(v.w); s += a + log1pf(__expf(-2.0f * a));
    s -= 4.0f * LN2;
    for (int off = 32; off; off >>= 1) s += __shfl_down(s, off, 64);
    __shared__ float red[4];
    if ((threadIdx.x & 63) == 0) red[threadIdx.x >> 6] = s;
    __syncthreads();
    if (threadIdx.x == 0) out[row] = red[0] + red[1] + red[2] + red[3];
}

extern "C" void kernel_launch(void* const* d_in, const int* in_sizes, int n_in,
                              void* d_out, int out_size, void* d_ws, size_t ws_size,
                              hipStream_t stream)
{
    (void)in_sizes; (void)n_in; (void)out_size; (void)ws_size;

    const float* x    = (const float*)d_in[0];
    const float* W_in = (const float*)d_in[1];
    const float* b_in = (const float*)d_in[2];
    const float* Wq   = (const float*)d_in[3];
    const float* Wk   = (const float*)d_in[4];
    const float* Wv   = (const float*)d_in[5];
    float* out = (float*)d_out;

    // ---- workspace carve, total ~200 MiB (aliased lifetimes) ----
    // [0, 128M)      : P bf16 [N,N]  (exp(S-64), written by S-GEMM epilogue)
    // [128M, 144M)   : xb (x bf16; dead after h-GEMM) -> vtb (v^T bf16 [H,N])
    // [144M, 160M)   : hb (h bf16; dead after vT-GEMM)
    // [160M, 192M)   : qk bf16 [N, 2048] (q | k); dead after S-GEMM -> outf
    // [192M, 200M)   : wib, wqb, wkb, wvb (2 MiB each; wqb+wkb contiguous!)
    // [200M, ...)    : pz (column sums of P, atomic-accumulated)
    char* w = (char*)d_ws;
    const size_t MiB = 1024 * 1024;
    unsigned short* Pb     = (unsigned short*)(w);                 // S->P
    unsigned short* xb     = (unsigned short*)(w + 128 * MiB);
    unsigned short* vtb    = (unsigned short*)(w + 128 * MiB);     // alias xb
    unsigned short* hb     = (unsigned short*)(w + 144 * MiB);
    unsigned short* qk     = (unsigned short*)(w + 160 * MiB);
    float*          outf   = (float*)         (w + 160 * MiB);     // alias qk
    unsigned short* wib    = (unsigned short*)(w + 192 * MiB);
    unsigned short* wqkb   = (unsigned short*)(w + 194 * MiB);     // [Wq;Wk] 2048x1024
    unsigned short* wqb    = (unsigned short*)(w + 194 * MiB);
    unsigned short* wkb    = (unsigned short*)(w + 196 * MiB);
    unsigned short* wvb    = (unsigned short*)(w + 198 * MiB);
    float*          pz     = (float*)         (w + 200 * MiB);

    // 1) fp32 -> bf16 converts; zero the z accumulator
    {
        int n4x = NTOK * NHID / 4;      // 2M
        int n4w = NHID * NHID / 4;      // 256K
        cvt_f32_bf16<<<(n4x + 255) / 256, 256, 0, stream>>>((const float4*)x,    (ushort4*)xb,  n4x);
        cvt_f32_bf16<<<(n4w + 255) / 256, 256, 0, stream>>>((const float4*)W_in, (ushort4*)wib, n4w);
        cvt_f32_bf16<<<(n4w + 255) / 256, 256, 0, stream>>>((const float4*)Wq,   (ushort4*)wqb, n4w);
        cvt_f32_bf16<<<(n4w + 255) / 256, 256, 0, stream>>>((const float4*)Wk,   (ushort4*)wkb, n4w);
        cvt_f32_bf16<<<(n4w + 255) / 256, 256, 0, stream>>>((const float4*)Wv,   (ushort4*)wvb, n4w);
        hipMemsetAsync(pz, 0, NTOK * sizeof(float), stream);
    }

    // 2) h = x @ W_in^T + b_in   -> bf16 [N,H]   (reads xb, writes hb)
    dim3 gNH(NHID / 128, NTOK / 128);   // (8, 64)
    gemm_bt<1, false, 1><<<gNH, 256, 0, stream>>>(
        xb, wib, hb, b_in, nullptr, 1.0f, NTOK, NHID, NHID, NHID, NHID);

    // 3) [q|k] = h @ [Wq;Wk]^T -> qk [N, 2048]   (single fused GEMM)
    dim3 gQK(2 * NHID / 128, NTOK / 128);  // (16, 64)
    gemm_bt<1, false, 1><<<gQK, 256, 0, stream>>>(
        hb, wqkb, qk, nullptr, nullptr, 1.0f, NTOK, 2 * NHID, NHID, NHID, NHID);

    // 4) v^T = Wv @ h^T -> vtb [H, N]  (vtb aliases dead xb; hb dead after)
    dim3 gVT(NTOK / 128, NHID / 128);   // (64, 8)
    gemm_bt<1, false, 1><<<gVT, 256, 0, stream>>>(
        wvb, hb, vtb, nullptr, nullptr, 1.0f, NHID, NTOK, NHID, NHID, NHID);

    // 5) P = exp(0.25 * q @ k^T - 64) -> bf16 [N,N]; fused z_j = sum_i P[i,j]
    //    q = qk[:,0:1024] (lda=2048), k = qk[:,1024:2048] (ldb=2048)
    dim3 gS(NTOK / 128, NTOK / 128);    // (64, 64)
    gemm_bt<2, false, 1><<<gS, 256, 0, stream>>>(
        qk, qk + NHID, Pb, nullptr, pz, 0.25f, NTOK, NTOK, NHID, 2 * NHID, 2 * NHID);

    // 6) qk now dead -> zero outf (split-K accumulator); fold 1/z into v^T
    hipMemsetAsync(outf, 0, (size_t)NTOK * NHID * sizeof(float), stream);
    vt_scale<<<(NHID * NTOK / 8) / 256, 256, 0, stream>>>((uint4*)vtb, pz);

    // 7) out = P @ v'^T -> fp32 [N,H], split-K=4 atomic accumulation
    //    SWAP grid: row-blocks dispatch-fastest -> A (P) L3-resident re-read
    dim3 gO(NTOK / 128, NHID / 128, 4);    // (64, 8, 4) = 2048 blocks
    gemm_bt<0, true, 4><<<gO, 256, 0, stream>>>(
        Pb, vtb, outf, nullptr, nullptr, 1.0f, NTOK, NHID, NTOK, NTOK, NTOK);

    // 8) d_out[i] = sum_h logcosh(outf[i,h])
    logcosh_rowsum<<<NTOK, 256, 0, stream>>>((const float4*)outf, out);
}

// Round 7
// 548.849 us; speedup vs baseline: 1.0756x; 1.0756x over previous
//
#include <hip/hip_runtime.h>
#include <hip/hip_bf16.h>
#include <cstdint>
#include <cstddef>

// Problem constants
#define NTOK 8192   // N
#define NHID 1024   // hidden == n_spins

typedef __attribute__((ext_vector_type(8))) __bf16 bf16x8;
typedef __attribute__((ext_vector_type(4))) float f32x4;

__device__ __forceinline__ unsigned short f2bf(float f) {
    union { float f; unsigned u; } v; v.f = f;
    unsigned r = v.u + 0x7FFF + ((v.u >> 16) & 1);   // RNE
    return (unsigned short)(r >> 16);
}

__device__ __forceinline__ float bf2f(unsigned short u) {
    union { unsigned u; float f; } v; v.u = ((unsigned)u) << 16;
    return v.f;
}

__device__ __forceinline__ void async_copy16(const void* gsrc, void* ldsdst) {
    __builtin_amdgcn_global_load_lds(
        (const __attribute__((address_space(1))) unsigned int*)gsrc,
        (__attribute__((address_space(3))) unsigned int*)ldsdst,
        16, 0, 0);
}

// ---------------------------------------------------------------------------
// C[M,N] = epilogue( scale * (A[M,K] @ B[N,K]^T) + bias )  (A,B bf16)
// A row stride = lda, B row stride = ldb, C row stride = N (elements).
// EPI 0: fp32 store, linear          EPI 1: bf16 store, linear
// EPI 2: bf16 store, exp(scale*acc - 64) + fused column-sum atomicAdd to zsum
// SWAP: bm from blockIdx.x (row-blocks dispatch-fastest) — L3 locality for
//       tall-skinny C where A is the big re-read operand (attn@v):
//       R5 evidence FETCH 534->175 MB.
// NOTE R6: split-K=4 on attn@v FAILED — occupancy 20->30% but dur 180->190 µs
//       and +128 MiB atomic write traffic. The limiter is the K-loop barrier
//       structure (m102 plateau), not resident-block count. Keep SPLITK out.
// m97 structure: 128x128 tile, BK=64, 256 thr (4 waves, each 64x64),
// global_load_lds width=16 staging, mfma_f32_16x16x32_bf16.
// LDS bank-conflict fix: XOR swizzle chunk' = chunk ^ (row&7) within each
// 128-B LDS row, applied on the global-source side of staging and mirrored
// in the ds_read fragment addressing (R4: conflicts 5.03e7 -> 0).
// M,N multiples of 128; K multiple of 64.
// ---------------------------------------------------------------------------
template <int EPI, bool SWAP>
__global__ __launch_bounds__(256) void gemm_bt(
    const unsigned short* __restrict__ A,
    const unsigned short* __restrict__ B,
    void* __restrict__ C,
    const float* __restrict__ bias,
    float* __restrict__ zsum,
    float scale, int M, int N, int K, int lda, int ldb)
{
    __shared__ __attribute__((aligned(16))) unsigned short As[128 * 64];
    __shared__ __attribute__((aligned(16))) unsigned short Bs[128 * 64];

    const int tid  = threadIdx.x;
    const int wave = tid >> 6;
    const int lane = tid & 63;
    const int bm = (SWAP ? blockIdx.x : blockIdx.y) * 128;
    const int bn = (SWAP ? blockIdx.y : blockIdx.x) * 128;
    const size_t ldaz = (size_t)lda;
    const size_t ldbz = (size_t)ldb;

    // staging: per wave, 4 issues of 16B/lane for A and B each.
    // LDS layout [row][k], 64 bf16 per row (128B), chunk XOR-swizzled by row&7.
    const int srow = lane >> 3;                        // 0..7 == row&7
    const int scol = ((lane & 7) ^ srow) * 8;          // swizzled k-chunk
    const unsigned short* Ag[4];
    const unsigned short* Bg[4];
    unsigned short* Al[4];
    unsigned short* Bl[4];
#pragma unroll
    for (int t = 0; t < 4; ++t) {
        int r = (wave * 4 + t) * 8 + srow;
        Ag[t] = A + (size_t)(bm + r) * ldaz + scol;
        Bg[t] = B + (size_t)(bn + r) * ldbz + scol;
        Al[t] = &As[(wave * 4 + t) * 512];   // wave-uniform base; HW adds lane*16B
        Bl[t] = &Bs[(wave * 4 + t) * 512];
    }

    const int wm = (wave >> 1) * 64;
    const int wn = (wave & 1) * 64;
    const int fr = lane & 15;          // fragment row (m or n)
    const int frl = fr & 7;            // row&7 for swizzle
    const int q = lane >> 4;           // quad index 0..3

    f32x4 acc[4][4] = {};

    for (int kt = 0; kt < K; kt += 64) {
#pragma unroll
        for (int t = 0; t < 4; ++t) {
            async_copy16(Ag[t], Al[t]);
            async_copy16(Bg[t], Bl[t]);
            Ag[t] += 64;
            Bg[t] += 64;
        }
        __syncthreads();   // drains vmcnt for global_load_lds + barrier
#pragma unroll
        for (int ks = 0; ks < 2; ++ks) {
            const int pc = ((ks * 4 + q) ^ frl) * 8;   // swizzled chunk offset
            bf16x8 a[4], b[4];
#pragma unroll
            for (int i = 0; i < 4; ++i) {
                a[i] = *(const bf16x8*)&As[(wm + i * 16 + fr) * 64 + pc];
                b[i] = *(const bf16x8*)&Bs[(wn + i * 16 + fr) * 64 + pc];
            }
#pragma unroll
            for (int i = 0; i < 4; ++i)
#pragma unroll
                for (int j = 0; j < 4; ++j)
                    acc[i][j] = __builtin_amdgcn_mfma_f32_16x16x32_bf16(
                        a[i], b[j], acc[i][j], 0, 0, 0);
        }
        __syncthreads();
    }

    // epilogue: D[row=(lane>>4)*4+r][col=lane&15] per 16x16 tile (verified map)
    const int erow = q * 4;
#pragma unroll
    for (int j = 0; j < 4; ++j) {
        const int gcol = bn + wn + j * 16 + fr;
        const float bv = (EPI != 2 && bias) ? bias[gcol] : 0.0f;
        float colsum = 0.0f;
#pragma unroll
        for (int i = 0; i < 4; ++i) {
            const int grow0 = bm + wm + i * 16 + erow;
#pragma unroll
            for (int r = 0; r < 4; ++r) {
                float v;
                if (EPI == 2) {
                    // P = exp(scale*acc - 64): fixed-shift softmax numerator.
                    // scores ~ N(0,8^2), max ~48 << 64+87 (bf16 floor), so no
                    // overflow and column-relevant terms never underflow.
                    v = __expf(fmaf(acc[i][j][r], scale, -64.0f));
                    colsum += v;
                } else {
                    v = acc[i][j][r] * scale + bv;
                }
                size_t idx = (size_t)(grow0 + r) * N + gcol;
                if (EPI == 0) ((float*)C)[idx] = v;
                else          ((unsigned short*)C)[idx] = f2bf(v);
            }
        }
        if (EPI == 2) {
            // reduce over the 4 quad-lanes holding this column (lane ^16, ^32)
            colsum += __shfl_xor(colsum, 16, 64);
            colsum += __shfl_xor(colsum, 32, 64);
            if (q == 0) atomicAdd(&zsum[gcol], colsum);
        }
    }
}

// fused fp32->bf16 convert for x (n4x float4s) + 4 weight mats (n4w each)
// into xb and the CONTIGUOUS weight region wdst (wib|wqb|wkb|wvb).
__global__ void cvt_all(const float4* __restrict__ x,
                        const float4* __restrict__ w0,
                        const float4* __restrict__ w1,
                        const float4* __restrict__ w2,
                        const float4* __restrict__ w3,
                        ushort4* __restrict__ xb,
                        ushort4* __restrict__ wdst,
                        int n4x, int n4w)
{
    int i = blockIdx.x * blockDim.x + threadIdx.x;
    float4 f;
    ushort4* dst;
    if (i < n4x) {
        f = x[i]; dst = xb + i;
    } else {
        int r = i - n4x;
        int seg = r / n4w, off = r % n4w;
        const float4* src = (seg == 0) ? w0 : (seg == 1) ? w1 : (seg == 2) ? w2 : w3;
        f = src[off]; dst = wdst + r;
    }
    ushort4 o;
    o.x = f2bf(f.x); o.y = f2bf(f.y); o.z = f2bf(f.z); o.w = f2bf(f.w);
    *dst = o;
}

// v^T[h][j] *= 1/z_j   (in place on bf16 vtb, 8 j's per thread)
__global__ void vt_scale(uint4* __restrict__ vt8,
                         const float* __restrict__ z)
{
    int idx = blockIdx.x * blockDim.x + threadIdx.x;  // 0 .. H*N/8-1
    int jj = (idx & (NTOK / 8 - 1)) * 8;
    uint4 v = vt8[idx];
    unsigned short* vp = (unsigned short*)&v;
    float4 z0 = *(const float4*)&z[jj];
    float4 z1 = *(const float4*)&z[jj + 4];
    uint4 o;
    unsigned short* op = (unsigned short*)&o;
    op[0] = f2bf(bf2f(vp[0]) / z0.x);
    op[1] = f2bf(bf2f(vp[1]) / z0.y);
    op[2] = f2bf(bf2f(vp[2]) / z0.z);
    op[3] = f2bf(bf2f(vp[3]) / z0.w);
    op[4] = f2bf(bf2f(vp[4]) / z1.x);
    op[5] = f2bf(bf2f(vp[5]) / z1.y);
    op[6] = f2bf(bf2f(vp[6]) / z1.z);
    op[7] = f2bf(bf2f(vp[7]) / z1.w);
    vt8[idx] = o;
}

// d_out[row] = sum_h logcosh(out[row,h]); bf16 input, one block/row,
// 256 thr x 4 elems (ushort4 = 8B load)
__global__ void logcosh_rowsum(const ushort4* __restrict__ O4,
                               float* __restrict__ out)
{
    const float LN2 = 0.69314718055994531f;
    int row = blockIdx.x;
    ushort4 u = O4[(size_t)row * 256 + threadIdx.x];
    float s = 0.0f, a;
    a = fabsf(bf2f(u.x)); s += a + log1pf(__expf(-2.0f * a));
    a = fabsf(bf2f(u.y)); s += a + log1pf(__expf(-2.0f * a));
    a = fabsf(bf2f(u.z)); s += a + log1pf(__expf(-2.0f * a));
    a = fabsf(bf2f(u.w)); s += a + log1pf(__expf(-2.0f * a));
    s -= 4.0f * LN2;
    for (int off = 32; off; off >>= 1) s += __shfl_down(s, off, 64);
    __shared__ float red[4];
    if ((threadIdx.x & 63) == 0) red[threadIdx.x >> 6] = s;
    __syncthreads();
    if (threadIdx.x == 0) out[row] = red[0] + red[1] + red[2] + red[3];
}

extern "C" void kernel_launch(void* const* d_in, const int* in_sizes, int n_in,
                              void* d_out, int out_size, void* d_ws, size_t ws_size,
                              hipStream_t stream)
{
    (void)in_sizes; (void)n_in; (void)out_size; (void)ws_size;

    const float* x    = (const float*)d_in[0];
    const float* W_in = (const float*)d_in[1];
    const float* b_in = (const float*)d_in[2];
    const float* Wq   = (const float*)d_in[3];
    const float* Wk   = (const float*)d_in[4];
    const float* Wv   = (const float*)d_in[5];
    float* out = (float*)d_out;

    // ---- workspace carve, total ~200 MiB (aliased lifetimes) ----
    // [0, 128M)      : P bf16 [N,N]  (exp(S-64), written by S-GEMM epilogue)
    // [128M, 144M)   : xb (x bf16; dead after h-GEMM) -> vtb (v^T bf16 [H,N])
    // [144M, 160M)   : hb (h bf16; dead after vT-GEMM)
    // [160M, 192M)   : qk bf16 [N, 2048] (q | k); dead after S-GEMM -> outb
    // [192M, 200M)   : wib|wqb|wkb|wvb (2 MiB each, contiguous)
    // [200M, ...)    : pz (column sums of P, atomic-accumulated)
    char* w = (char*)d_ws;
    const size_t MiB = 1024 * 1024;
    unsigned short* Pb     = (unsigned short*)(w);                 // S->P
    unsigned short* xb     = (unsigned short*)(w + 128 * MiB);
    unsigned short* vtb    = (unsigned short*)(w + 128 * MiB);     // alias xb
    unsigned short* hb     = (unsigned short*)(w + 144 * MiB);
    unsigned short* qk     = (unsigned short*)(w + 160 * MiB);
    unsigned short* outb   = (unsigned short*)(w + 160 * MiB);     // alias qk
    unsigned short* wib    = (unsigned short*)(w + 192 * MiB);
    unsigned short* wqkb   = (unsigned short*)(w + 194 * MiB);     // [Wq;Wk] 2048x1024
    unsigned short* wvb    = (unsigned short*)(w + 198 * MiB);
    float*          pz     = (float*)         (w + 200 * MiB);

    // 1) fp32 -> bf16 converts (one fused launch); zero the z accumulator
    {
        int n4x = NTOK * NHID / 4;      // 2M float4
        int n4w = NHID * NHID / 4;      // 256K float4 per weight
        int n4  = n4x + 4 * n4w;        // 3M total
        cvt_all<<<(n4 + 255) / 256, 256, 0, stream>>>(
            (const float4*)x, (const float4*)W_in, (const float4*)Wq,
            (const float4*)Wk, (const float4*)Wv,
            (ushort4*)xb, (ushort4*)wib, n4x, n4w);
        hipMemsetAsync(pz, 0, NTOK * sizeof(float), stream);
    }

    // 2) h = x @ W_in^T + b_in   -> bf16 [N,H]   (reads xb, writes hb)
    dim3 gNH(NHID / 128, NTOK / 128);   // (8, 64)
    gemm_bt<1, false><<<gNH, 256, 0, stream>>>(
        xb, wib, hb, b_in, nullptr, 1.0f, NTOK, NHID, NHID, NHID, NHID);

    // 3) [q|k] = h @ [Wq;Wk]^T -> qk [N, 2048]   (single fused GEMM)
    dim3 gQK(2 * NHID / 128, NTOK / 128);  // (16, 64)
    gemm_bt<1, false><<<gQK, 256, 0, stream>>>(
        hb, wqkb, qk, nullptr, nullptr, 1.0f, NTOK, 2 * NHID, NHID, NHID, NHID);

    // 4) v^T = Wv @ h^T -> vtb [H, N]  (vtb aliases dead xb; hb dead after)
    dim3 gVT(NTOK / 128, NHID / 128);   // (64, 8)
    gemm_bt<1, false><<<gVT, 256, 0, stream>>>(
        wvb, hb, vtb, nullptr, nullptr, 1.0f, NHID, NTOK, NHID, NHID, NHID);

    // 5) P = exp(0.25 * q @ k^T - 64) -> bf16 [N,N]; fused z_j = sum_i P[i,j]
    //    q = qk[:,0:1024] (lda=2048), k = qk[:,1024:2048] (ldb=2048)
    dim3 gS(NTOK / 128, NTOK / 128);    // (64, 64)
    gemm_bt<2, false><<<gS, 256, 0, stream>>>(
        qk, qk + NHID, Pb, nullptr, pz, 0.25f, NTOK, NTOK, NHID, 2 * NHID, 2 * NHID);

    // 6) fold normalization into v^T:  vtb[h][j] /= z_j
    vt_scale<<<(NHID * NTOK / 8) / 256, 256, 0, stream>>>((uint4*)vtb, pz);

    // 7) out = P @ v'^T -> bf16 [N,H]  (outb aliases dead qk)
    //    SWAP grid: row-blocks dispatch-fastest -> A (P) L3-resident re-read
    dim3 gO(NTOK / 128, NHID / 128);    // (64, 8) with SWAP mapping
    gemm_bt<1, true><<<gO, 256, 0, stream>>>(
        Pb, vtb, outb, nullptr, nullptr, 1.0f, NTOK, NHID, NTOK, NTOK, NTOK);

    // 8) d_out[i] = sum_h logcosh(outb[i,h])
    logcosh_rowsum<<<NTOK, 256, 0, stream>>>((const ushort4*)outb, out);
}

// Round 8
// 548.359 us; speedup vs baseline: 1.0766x; 1.0009x over previous
//
#include <hip/hip_runtime.h>
#include <hip/hip_bf16.h>
#include <cstdint>
#include <cstddef>

// Problem constants
#define NTOK 8192   // N
#define NHID 1024   // hidden == n_spins

typedef __attribute__((ext_vector_type(8))) __bf16 bf16x8;
typedef __attribute__((ext_vector_type(4))) float f32x4;

__device__ __forceinline__ unsigned short f2bf(float f) {
    union { float f; unsigned u; } v; v.f = f;
    unsigned r = v.u + 0x7FFF + ((v.u >> 16) & 1);   // RNE
    return (unsigned short)(r >> 16);
}

__device__ __forceinline__ float bf2f(unsigned short u) {
    union { unsigned u; float f; } v; v.u = ((unsigned)u) << 16;
    return v.f;
}

__device__ __forceinline__ void async_copy16(const void* gsrc, void* ldsdst) {
    __builtin_amdgcn_global_load_lds(
        (const __attribute__((address_space(1))) unsigned int*)gsrc,
        (__attribute__((address_space(3))) unsigned int*)ldsdst,
        16, 0, 0);
}

// ---------------------------------------------------------------------------
// C[M,N] = epilogue( scale * (A[M,K] @ B[N,K]^T) + bias )  (A,B bf16)
// A row stride = lda, B row stride = ldb, C row stride = N (elements).
// EPI 0: fp32 store, linear          EPI 1: bf16 store, linear
// EPI 2: bf16 store, exp(scale*acc - 64) + fused column-sum atomicAdd to zsum
// EPI 3: NO C store; logcosh(acc) row-reduced and atomicAdd'd into zsum[row]
//        (zsum = d_out, must be zero-initialized) — fuses the final
//        sum_h logcosh(out) into the attn@v GEMM epilogue.
// SWAP: bm from blockIdx.x (row-blocks dispatch-fastest) — L3 locality for
//       tall-skinny C where A is the big re-read operand (attn@v):
//       R5 evidence FETCH 534->175 MB.
// NOTE R6: split-K=4 on attn@v FAILED — occupancy 20->30% but dur 180->190 µs
//       and +128 MiB atomic write traffic. The limiter is the K-loop barrier
//       structure (m102 plateau), not resident-block count. Keep SPLITK out.
// m97 structure: 128x128 tile, BK=64, 256 thr (4 waves, each 64x64),
// global_load_lds width=16 staging, mfma_f32_16x16x32_bf16.
// LDS bank-conflict fix: XOR swizzle chunk' = chunk ^ (row&7) within each
// 128-B LDS row, applied on the global-source side of staging and mirrored
// in the ds_read fragment addressing (R4: conflicts 5.03e7 -> 0).
// M,N multiples of 128; K multiple of 64.
// ---------------------------------------------------------------------------
template <int EPI, bool SWAP>
__global__ __launch_bounds__(256) void gemm_bt(
    const unsigned short* __restrict__ A,
    const unsigned short* __restrict__ B,
    void* __restrict__ C,
    const float* __restrict__ bias,
    float* __restrict__ zsum,
    float scale, int M, int N, int K, int lda, int ldb)
{
    __shared__ __attribute__((aligned(16))) unsigned short As[128 * 64];
    __shared__ __attribute__((aligned(16))) unsigned short Bs[128 * 64];

    const int tid  = threadIdx.x;
    const int wave = tid >> 6;
    const int lane = tid & 63;
    const int bm = (SWAP ? blockIdx.x : blockIdx.y) * 128;
    const int bn = (SWAP ? blockIdx.y : blockIdx.x) * 128;
    const size_t ldaz = (size_t)lda;
    const size_t ldbz = (size_t)ldb;

    // staging: per wave, 4 issues of 16B/lane for A and B each.
    // LDS layout [row][k], 64 bf16 per row (128B), chunk XOR-swizzled by row&7.
    const int srow = lane >> 3;                        // 0..7 == row&7
    const int scol = ((lane & 7) ^ srow) * 8;          // swizzled k-chunk
    const unsigned short* Ag[4];
    const unsigned short* Bg[4];
    unsigned short* Al[4];
    unsigned short* Bl[4];
#pragma unroll
    for (int t = 0; t < 4; ++t) {
        int r = (wave * 4 + t) * 8 + srow;
        Ag[t] = A + (size_t)(bm + r) * ldaz + scol;
        Bg[t] = B + (size_t)(bn + r) * ldbz + scol;
        Al[t] = &As[(wave * 4 + t) * 512];   // wave-uniform base; HW adds lane*16B
        Bl[t] = &Bs[(wave * 4 + t) * 512];
    }

    const int wm = (wave >> 1) * 64;
    const int wn = (wave & 1) * 64;
    const int fr = lane & 15;          // fragment row (m or n)
    const int frl = fr & 7;            // row&7 for swizzle
    const int q = lane >> 4;           // quad index 0..3

    f32x4 acc[4][4] = {};

    for (int kt = 0; kt < K; kt += 64) {
#pragma unroll
        for (int t = 0; t < 4; ++t) {
            async_copy16(Ag[t], Al[t]);
            async_copy16(Bg[t], Bl[t]);
            Ag[t] += 64;
            Bg[t] += 64;
        }
        __syncthreads();   // drains vmcnt for global_load_lds + barrier
#pragma unroll
        for (int ks = 0; ks < 2; ++ks) {
            const int pc = ((ks * 4 + q) ^ frl) * 8;   // swizzled chunk offset
            bf16x8 a[4], b[4];
#pragma unroll
            for (int i = 0; i < 4; ++i) {
                a[i] = *(const bf16x8*)&As[(wm + i * 16 + fr) * 64 + pc];
                b[i] = *(const bf16x8*)&Bs[(wn + i * 16 + fr) * 64 + pc];
            }
#pragma unroll
            for (int i = 0; i < 4; ++i)
#pragma unroll
                for (int j = 0; j < 4; ++j)
                    acc[i][j] = __builtin_amdgcn_mfma_f32_16x16x32_bf16(
                        a[i], b[j], acc[i][j], 0, 0, 0);
        }
        __syncthreads();
    }

    // epilogue: D[row=(lane>>4)*4+r][col=lane&15] per 16x16 tile (verified map)
    const int erow = q * 4;
    const float LN2 = 0.69314718055994531f;
    float lcsum[16];   // EPI==3: per-(i,r) row partials across this lane's cols
    if (EPI == 3) {
#pragma unroll
        for (int t = 0; t < 16; ++t) lcsum[t] = 0.0f;
    }
#pragma unroll
    for (int j = 0; j < 4; ++j) {
        const int gcol = bn + wn + j * 16 + fr;
        const float bv = (EPI == 1 && bias) ? bias[gcol] : 0.0f;
        float colsum = 0.0f;
#pragma unroll
        for (int i = 0; i < 4; ++i) {
            const int grow0 = bm + wm + i * 16 + erow;
#pragma unroll
            for (int r = 0; r < 4; ++r) {
                float v;
                if (EPI == 2) {
                    // P = exp(scale*acc - 64): fixed-shift softmax numerator.
                    // scores ~ N(0,8^2), max ~48 << 64+87 (bf16 floor), so no
                    // overflow and column-relevant terms never underflow.
                    v = __expf(fmaf(acc[i][j][r], scale, -64.0f));
                    colsum += v;
                } else {
                    v = acc[i][j][r] * scale + bv;
                }
                if (EPI == 3) {
                    float a = fabsf(v);
                    lcsum[i * 4 + r] += a + log1pf(__expf(-2.0f * a)) - LN2;
                } else {
                    size_t idx = (size_t)(grow0 + r) * N + gcol;
                    if (EPI == 0) ((float*)C)[idx] = v;
                    else          ((unsigned short*)C)[idx] = f2bf(v);
                }
            }
        }
        if (EPI == 2) {
            // reduce over the 4 quad-lanes holding this column (lane ^16, ^32)
            colsum += __shfl_xor(colsum, 16, 64);
            colsum += __shfl_xor(colsum, 32, 64);
            if (q == 0) atomicAdd(&zsum[gcol], colsum);
        }
    }
    if (EPI == 3) {
        // reduce each row-partial across the 16 fr-lanes of this quad group
#pragma unroll
        for (int t = 0; t < 16; ++t) {
            lcsum[t] += __shfl_xor(lcsum[t], 1, 64);
            lcsum[t] += __shfl_xor(lcsum[t], 2, 64);
            lcsum[t] += __shfl_xor(lcsum[t], 4, 64);
            lcsum[t] += __shfl_xor(lcsum[t], 8, 64);
        }
        if (fr == 0) {
#pragma unroll
            for (int i = 0; i < 4; ++i)
#pragma unroll
                for (int r = 0; r < 4; ++r)
                    atomicAdd(&zsum[bm + wm + i * 16 + erow + r],
                              lcsum[i * 4 + r]);
        }
    }
}

// fused fp32->bf16 convert for x (n4x float4s) + 4 weight mats (n4w each)
// into xb and the CONTIGUOUS weight region wdst (wib|wqb|wkb|wvb).
__global__ void cvt_all(const float4* __restrict__ x,
                        const float4* __restrict__ w0,
                        const float4* __restrict__ w1,
                        const float4* __restrict__ w2,
                        const float4* __restrict__ w3,
                        ushort4* __restrict__ xb,
                        ushort4* __restrict__ wdst,
                        int n4x, int n4w)
{
    int i = blockIdx.x * blockDim.x + threadIdx.x;
    float4 f;
    ushort4* dst;
    if (i < n4x) {
        f = x[i]; dst = xb + i;
    } else {
        int r = i - n4x;
        int seg = r / n4w, off = r % n4w;
        const float4* src = (seg == 0) ? w0 : (seg == 1) ? w1 : (seg == 2) ? w2 : w3;
        f = src[off]; dst = wdst + r;
    }
    ushort4 o;
    o.x = f2bf(f.x); o.y = f2bf(f.y); o.z = f2bf(f.z); o.w = f2bf(f.w);
    *dst = o;
}

// v^T[h][j] *= 1/z_j   (in place on bf16 vtb, 8 j's per thread)
__global__ void vt_scale(uint4* __restrict__ vt8,
                         const float* __restrict__ z)
{
    int idx = blockIdx.x * blockDim.x + threadIdx.x;  // 0 .. H*N/8-1
    int jj = (idx & (NTOK / 8 - 1)) * 8;
    uint4 v = vt8[idx];
    unsigned short* vp = (unsigned short*)&v;
    float4 z0 = *(const float4*)&z[jj];
    float4 z1 = *(const float4*)&z[jj + 4];
    uint4 o;
    unsigned short* op = (unsigned short*)&o;
    op[0] = f2bf(bf2f(vp[0]) / z0.x);
    op[1] = f2bf(bf2f(vp[1]) / z0.y);
    op[2] = f2bf(bf2f(vp[2]) / z0.z);
    op[3] = f2bf(bf2f(vp[3]) / z0.w);
    op[4] = f2bf(bf2f(vp[4]) / z1.x);
    op[5] = f2bf(bf2f(vp[5]) / z1.y);
    op[6] = f2bf(bf2f(vp[6]) / z1.z);
    op[7] = f2bf(bf2f(vp[7]) / z1.w);
    vt8[idx] = o;
}

extern "C" void kernel_launch(void* const* d_in, const int* in_sizes, int n_in,
                              void* d_out, int out_size, void* d_ws, size_t ws_size,
                              hipStream_t stream)
{
    (void)in_sizes; (void)n_in; (void)out_size; (void)ws_size;

    const float* x    = (const float*)d_in[0];
    const float* W_in = (const float*)d_in[1];
    const float* b_in = (const float*)d_in[2];
    const float* Wq   = (const float*)d_in[3];
    const float* Wk   = (const float*)d_in[4];
    const float* Wv   = (const float*)d_in[5];
    float* out = (float*)d_out;

    // ---- workspace carve, total ~200 MiB (aliased lifetimes) ----
    // [0, 128M)      : P bf16 [N,N]  (exp(S-64), written by S-GEMM epilogue)
    // [128M, 144M)   : xb (x bf16; dead after h-GEMM) -> vtb (v^T bf16 [H,N])
    // [144M, 160M)   : hb (h bf16; dead after vT-GEMM)
    // [160M, 192M)   : qk bf16 [N, 2048] (q | k); dead after S-GEMM
    // [192M, 200M)   : wib|wqb|wkb|wvb (2 MiB each, contiguous)
    // [200M, ...)    : pz (column sums of P, atomic-accumulated)
    char* w = (char*)d_ws;
    const size_t MiB = 1024 * 1024;
    unsigned short* Pb     = (unsigned short*)(w);                 // S->P
    unsigned short* xb     = (unsigned short*)(w + 128 * MiB);
    unsigned short* vtb    = (unsigned short*)(w + 128 * MiB);     // alias xb
    unsigned short* hb     = (unsigned short*)(w + 144 * MiB);
    unsigned short* qk     = (unsigned short*)(w + 160 * MiB);
    unsigned short* wib    = (unsigned short*)(w + 192 * MiB);
    unsigned short* wqkb   = (unsigned short*)(w + 194 * MiB);     // [Wq;Wk] 2048x1024
    unsigned short* wvb    = (unsigned short*)(w + 198 * MiB);
    float*          pz     = (float*)         (w + 200 * MiB);

    // 1) fp32 -> bf16 converts (one fused launch); zero z accumulator + d_out
    {
        int n4x = NTOK * NHID / 4;      // 2M float4
        int n4w = NHID * NHID / 4;      // 256K float4 per weight
        int n4  = n4x + 4 * n4w;        // 3M total
        cvt_all<<<(n4 + 255) / 256, 256, 0, stream>>>(
            (const float4*)x, (const float4*)W_in, (const float4*)Wq,
            (const float4*)Wk, (const float4*)Wv,
            (ushort4*)xb, (ushort4*)wib, n4x, n4w);
        hipMemsetAsync(pz, 0, NTOK * sizeof(float), stream);
        hipMemsetAsync(out, 0, NTOK * sizeof(float), stream);
    }

    // 2) h = x @ W_in^T + b_in   -> bf16 [N,H]   (reads xb, writes hb)
    dim3 gNH(NHID / 128, NTOK / 128);   // (8, 64)
    gemm_bt<1, false><<<gNH, 256, 0, stream>>>(
        xb, wib, hb, b_in, nullptr, 1.0f, NTOK, NHID, NHID, NHID, NHID);

    // 3) [q|k] = h @ [Wq;Wk]^T -> qk [N, 2048]   (single fused GEMM)
    dim3 gQK(2 * NHID / 128, NTOK / 128);  // (16, 64)
    gemm_bt<1, false><<<gQK, 256, 0, stream>>>(
        hb, wqkb, qk, nullptr, nullptr, 1.0f, NTOK, 2 * NHID, NHID, NHID, NHID);

    // 4) v^T = Wv @ h^T -> vtb [H, N]  (vtb aliases dead xb; hb dead after)
    dim3 gVT(NTOK / 128, NHID / 128);   // (64, 8)
    gemm_bt<1, false><<<gVT, 256, 0, stream>>>(
        wvb, hb, vtb, nullptr, nullptr, 1.0f, NHID, NTOK, NHID, NHID, NHID);

    // 5) P = exp(0.25 * q @ k^T - 64) -> bf16 [N,N]; fused z_j = sum_i P[i,j]
    //    q = qk[:,0:1024] (lda=2048), k = qk[:,1024:2048] (ldb=2048)
    dim3 gS(NTOK / 128, NTOK / 128);    // (64, 64)
    gemm_bt<2, false><<<gS, 256, 0, stream>>>(
        qk, qk + NHID, Pb, nullptr, pz, 0.25f, NTOK, NTOK, NHID, 2 * NHID, 2 * NHID);

    // 6) fold normalization into v^T:  vtb[h][j] /= z_j
    vt_scale<<<(NHID * NTOK / 8) / 256, 256, 0, stream>>>((uint4*)vtb, pz);

    // 7) out[i] = sum_h logcosh( (P @ v'^T)[i,h] )  — logcosh + row-sum fused
    //    into the GEMM epilogue (EPI=3, atomicAdd into zero-init'd d_out).
    //    SWAP grid: row-blocks dispatch-fastest -> A (P) L3-resident re-read
    dim3 gO(NTOK / 128, NHID / 128);    // (64, 8) with SWAP mapping
    gemm_bt<3, true><<<gO, 256, 0, stream>>>(
        Pb, vtb, nullptr, nullptr, out, 1.0f, NTOK, NHID, NTOK, NTOK, NTOK);
}

// Round 9
// 504.333 us; speedup vs baseline: 1.1705x; 1.0873x over previous
//
#include <hip/hip_runtime.h>
#include <hip/hip_bf16.h>
#include <cstdint>
#include <cstddef>

// Problem constants
#define NTOK 8192   // N
#define NHID 1024   // hidden == n_spins

typedef __attribute__((ext_vector_type(8))) __bf16 bf16x8;
typedef __attribute__((ext_vector_type(4))) float f32x4;

__device__ __forceinline__ unsigned short f2bf(float f) {
    union { float f; unsigned u; } v; v.f = f;
    unsigned r = v.u + 0x7FFF + ((v.u >> 16) & 1);   // RNE
    return (unsigned short)(r >> 16);
}

__device__ __forceinline__ float bf2f(unsigned short u) {
    union { unsigned u; float f; } v; v.u = ((unsigned)u) << 16;
    return v.f;
}

__device__ __forceinline__ void async_copy16(const void* gsrc, void* ldsdst) {
    __builtin_amdgcn_global_load_lds(
        (const __attribute__((address_space(1))) unsigned int*)gsrc,
        (__attribute__((address_space(3))) unsigned int*)ldsdst,
        16, 0, 0);
}

// ---------------------------------------------------------------------------
// C[M,N] = epilogue( scale * (A[M,K] @ B[N,K]^T) + bias )  (A,B bf16)
// A row stride = lda, B row stride = ldb, C row stride = N (elements).
// EPI 0: fp32 store, linear          EPI 1: bf16 store, linear
// EPI 2: bf16 store, exp(scale*acc - 64) + fused column-sum atomicAdd to zsum
// SWAP: bm from blockIdx.x (row-blocks dispatch-fastest) — L3 locality for
//       tall-skinny C where A is the big re-read operand (attn@v):
//       R5 evidence FETCH 534->175 MB.
// NOTE R6: split-K=4 on attn@v FAILED — occupancy 20->30% but dur 180->190 µs
//       and +128 MiB atomic write traffic. Limiter is the K-loop barrier
//       structure (m102 plateau), not resident-block count.
// NOTE R8: EPI=3 (logcosh row-sum fused into attn@v epilogue) FAILED —
//       dispatch 175->239 µs, MfmaUtil 33->24.8, VGPR 84->80: the 16-float
//       row-partial array on top of the 64-reg accumulator forced scratch
//       spills; the j-loop RMW of spilled lcsum is latency-bound. Keep the
//       epilogue store-only + separate memory-bound logcosh pass.
// m97 structure: 128x128 tile, BK=64, 256 thr (4 waves, each 64x64),
// global_load_lds width=16 staging, mfma_f32_16x16x32_bf16.
// LDS bank-conflict fix: XOR swizzle chunk' = chunk ^ (row&7) within each
// 128-B LDS row, applied on the global-source side of staging and mirrored
// in the ds_read fragment addressing (R4: conflicts 5.03e7 -> 0).
// M,N multiples of 128; K multiple of 64.
// ---------------------------------------------------------------------------
template <int EPI, bool SWAP>
__global__ __launch_bounds__(256) void gemm_bt(
    const unsigned short* __restrict__ A,
    const unsigned short* __restrict__ B,
    void* __restrict__ C,
    const float* __restrict__ bias,
    float* __restrict__ zsum,
    float scale, int M, int N, int K, int lda, int ldb)
{
    __shared__ __attribute__((aligned(16))) unsigned short As[128 * 64];
    __shared__ __attribute__((aligned(16))) unsigned short Bs[128 * 64];

    const int tid  = threadIdx.x;
    const int wave = tid >> 6;
    const int lane = tid & 63;
    const int bm = (SWAP ? blockIdx.x : blockIdx.y) * 128;
    const int bn = (SWAP ? blockIdx.y : blockIdx.x) * 128;
    const size_t ldaz = (size_t)lda;
    const size_t ldbz = (size_t)ldb;

    // staging: per wave, 4 issues of 16B/lane for A and B each.
    // LDS layout [row][k], 64 bf16 per row (128B), chunk XOR-swizzled by row&7.
    const int srow = lane >> 3;                        // 0..7 == row&7
    const int scol = ((lane & 7) ^ srow) * 8;          // swizzled k-chunk
    const unsigned short* Ag[4];
    const unsigned short* Bg[4];
    unsigned short* Al[4];
    unsigned short* Bl[4];
#pragma unroll
    for (int t = 0; t < 4; ++t) {
        int r = (wave * 4 + t) * 8 + srow;
        Ag[t] = A + (size_t)(bm + r) * ldaz + scol;
        Bg[t] = B + (size_t)(bn + r) * ldbz + scol;
        Al[t] = &As[(wave * 4 + t) * 512];   // wave-uniform base; HW adds lane*16B
        Bl[t] = &Bs[(wave * 4 + t) * 512];
    }

    const int wm = (wave >> 1) * 64;
    const int wn = (wave & 1) * 64;
    const int fr = lane & 15;          // fragment row (m or n)
    const int frl = fr & 7;            // row&7 for swizzle
    const int q = lane >> 4;           // quad index 0..3

    f32x4 acc[4][4] = {};

    for (int kt = 0; kt < K; kt += 64) {
#pragma unroll
        for (int t = 0; t < 4; ++t) {
            async_copy16(Ag[t], Al[t]);
            async_copy16(Bg[t], Bl[t]);
            Ag[t] += 64;
            Bg[t] += 64;
        }
        __syncthreads();   // drains vmcnt for global_load_lds + barrier
#pragma unroll
        for (int ks = 0; ks < 2; ++ks) {
            const int pc = ((ks * 4 + q) ^ frl) * 8;   // swizzled chunk offset
            bf16x8 a[4], b[4];
#pragma unroll
            for (int i = 0; i < 4; ++i) {
                a[i] = *(const bf16x8*)&As[(wm + i * 16 + fr) * 64 + pc];
                b[i] = *(const bf16x8*)&Bs[(wn + i * 16 + fr) * 64 + pc];
            }
#pragma unroll
            for (int i = 0; i < 4; ++i)
#pragma unroll
                for (int j = 0; j < 4; ++j)
                    acc[i][j] = __builtin_amdgcn_mfma_f32_16x16x32_bf16(
                        a[i], b[j], acc[i][j], 0, 0, 0);
        }
        __syncthreads();
    }

    // epilogue: D[row=(lane>>4)*4+r][col=lane&15] per 16x16 tile (verified map)
    const int erow = q * 4;
#pragma unroll
    for (int j = 0; j < 4; ++j) {
        const int gcol = bn + wn + j * 16 + fr;
        const float bv = (EPI == 1 && bias) ? bias[gcol] : 0.0f;
        float colsum = 0.0f;
#pragma unroll
        for (int i = 0; i < 4; ++i) {
            const int grow0 = bm + wm + i * 16 + erow;
#pragma unroll
            for (int r = 0; r < 4; ++r) {
                float v;
                if (EPI == 2) {
                    // P = exp(scale*acc - 64): fixed-shift softmax numerator.
                    // scores ~ N(0,8^2), max ~48 << 64+87 (bf16 floor), so no
                    // overflow and column-relevant terms never underflow.
                    v = __expf(fmaf(acc[i][j][r], scale, -64.0f));
                    colsum += v;
                } else {
                    v = acc[i][j][r] * scale + bv;
                }
                size_t idx = (size_t)(grow0 + r) * N + gcol;
                if (EPI == 0) ((float*)C)[idx] = v;
                else          ((unsigned short*)C)[idx] = f2bf(v);
            }
        }
        if (EPI == 2) {
            // reduce over the 4 quad-lanes holding this column (lane ^16, ^32)
            colsum += __shfl_xor(colsum, 16, 64);
            colsum += __shfl_xor(colsum, 32, 64);
            if (q == 0) atomicAdd(&zsum[gcol], colsum);
        }
    }
}

// fused fp32->bf16 convert for x (n4x float4s) + 4 weight mats (n4w each)
// into xb and the CONTIGUOUS weight region wdst (wib|wq|wk|wv).
// Extra 8 trailing blocks zero-fill pz (2048 float4 = 8192 floats).
__global__ void cvt_all(const float4* __restrict__ x,
                        const float4* __restrict__ w0,
                        const float4* __restrict__ w1,
                        const float4* __restrict__ w2,
                        const float4* __restrict__ w3,
                        ushort4* __restrict__ xb,
                        ushort4* __restrict__ wdst,
                        float4* __restrict__ pz4,
                        int n4x, int n4w)
{
    int i = blockIdx.x * blockDim.x + threadIdx.x;
    int n4 = n4x + 4 * n4w;
    if (i >= n4) {
        int zi = i - n4;
        if (zi < 2048) pz4[zi] = make_float4(0.f, 0.f, 0.f, 0.f);
        return;
    }
    float4 f;
    ushort4* dst;
    if (i < n4x) {
        f = x[i]; dst = xb + i;
    } else {
        int r = i - n4x;
        int seg = r / n4w, off = r % n4w;
        const float4* src = (seg == 0) ? w0 : (seg == 1) ? w1 : (seg == 2) ? w2 : w3;
        f = src[off]; dst = wdst + r;
    }
    ushort4 o;
    o.x = f2bf(f.x); o.y = f2bf(f.y); o.z = f2bf(f.z); o.w = f2bf(f.w);
    *dst = o;
}

// vt[h][j] = v[j][h] / z[j]; v is a [NTOK, NHID] view with row stride 3072
// (the v slice of qkv). 64x64 tile via float LDS (stride 65: (65c+r)%32 =
// (c+r)%32 -> 2 lanes/bank on reads = free per m136). Both global sides
// coalesced (128B/wave segments).
__global__ __launch_bounds__(256) void transpose_scale(
    const unsigned short* __restrict__ v,
    const float* __restrict__ z,
    unsigned short* __restrict__ vt)
{
    __shared__ float lds[64 * 65];
    const int tid = threadIdx.x;
    const int j0 = blockIdx.x * 64;
    const int h0 = blockIdx.y * 64;
    const int c = tid & 63;
    const int r0 = tid >> 6;     // 0..3
#pragma unroll
    for (int it = 0; it < 16; ++it) {
        int r = it * 4 + r0;     // j offset within tile
        lds[r * 65 + c] = bf2f(v[(size_t)(j0 + r) * 3072 + h0 + c]);
    }
    __syncthreads();
    const float rz = 1.0f / z[j0 + c];
#pragma unroll
    for (int it = 0; it < 16; ++it) {
        int r = it * 4 + r0;     // h offset within tile
        vt[(size_t)(h0 + r) * NTOK + j0 + c] = f2bf(lds[c * 65 + r] * rz);
    }
}

// d_out[row] = sum_h logcosh(out[row,h]); bf16 input, one block/row,
// 256 thr x 4 elems (ushort4 = 8B load)
__global__ void logcosh_rowsum(const ushort4* __restrict__ O4,
                               float* __restrict__ out)
{
    const float LN2 = 0.69314718055994531f;
    int row = blockIdx.x;
    ushort4 u = O4[(size_t)row * 256 + threadIdx.x];
    float s = 0.0f, a;
    a = fabsf(bf2f(u.x)); s += a + log1pf(__expf(-2.0f * a));
    a = fabsf(bf2f(u.y)); s += a + log1pf(__expf(-2.0f * a));
    a = fabsf(bf2f(u.z)); s += a + log1pf(__expf(-2.0f * a));
    a = fabsf(bf2f(u.w)); s += a + log1pf(__expf(-2.0f * a));
    s -= 4.0f * LN2;
    for (int off = 32; off; off >>= 1) s += __shfl_down(s, off, 64);
    __shared__ float red[4];
    if ((threadIdx.x & 63) == 0) red[threadIdx.x >> 6] = s;
    __syncthreads();
    if (threadIdx.x == 0) out[row] = red[0] + red[1] + red[2] + red[3];
}

extern "C" void kernel_launch(void* const* d_in, const int* in_sizes, int n_in,
                              void* d_out, int out_size, void* d_ws, size_t ws_size,
                              hipStream_t stream)
{
    (void)in_sizes; (void)n_in; (void)out_size; (void)ws_size;

    const float* x    = (const float*)d_in[0];
    const float* W_in = (const float*)d_in[1];
    const float* b_in = (const float*)d_in[2];
    const float* Wq   = (const float*)d_in[3];
    const float* Wk   = (const float*)d_in[4];
    const float* Wv   = (const float*)d_in[5];
    float* out = (float*)d_out;

    // ---- workspace carve, total ~200 MiB (aliased lifetimes) ----
    // [0, 128M)      : P bf16 [N,N]  (exp(S-64), written by S-GEMM epilogue)
    // [128M, 176M)   : qkv bf16 [N, 3072] (q|k|v), written step 3
    //                  - xb (x bf16) aliases [128M,144M): dead before step 3
    //                  - outb bf16 [N,H] aliases [128M,144M): q dead after
    //                    step 4, v (strided through whole region) dead after
    //                    step 5; outb written step 6
    // [176M, 192M)   : hb (h bf16; dead after qkv-GEMM) -> vtb [H,N] (step 5)
    // [192M, 200M)   : wib | wq | wk | wv (2 MiB each, contiguous;
    //                  [194M,200M) doubles as [Wq;Wk;Wv] stacked 3072x1024)
    // [200M, ...)    : pz (column sums of P, atomic-accumulated)
    char* w = (char*)d_ws;
    const size_t MiB = 1024 * 1024;
    unsigned short* Pb     = (unsigned short*)(w);                 // S->P
    unsigned short* qkv    = (unsigned short*)(w + 128 * MiB);
    unsigned short* xb     = (unsigned short*)(w + 128 * MiB);     // alias
    unsigned short* outb   = (unsigned short*)(w + 128 * MiB);     // alias
    unsigned short* hb     = (unsigned short*)(w + 176 * MiB);
    unsigned short* vtb    = (unsigned short*)(w + 176 * MiB);     // alias hb
    unsigned short* wib    = (unsigned short*)(w + 192 * MiB);
    unsigned short* wqkvb  = (unsigned short*)(w + 194 * MiB);     // [Wq;Wk;Wv]
    float*          pz     = (float*)         (w + 200 * MiB);

    // 1) fp32 -> bf16 converts + pz zero-fill (single launch)
    {
        int n4x = NTOK * NHID / 4;      // 2M float4
        int n4w = NHID * NHID / 4;      // 256K float4 per weight
        int n4  = n4x + 4 * n4w;        // 3M total (divisible by 256)
        cvt_all<<<n4 / 256 + 8, 256, 0, stream>>>(
            (const float4*)x, (const float4*)W_in, (const float4*)Wq,
            (const float4*)Wk, (const float4*)Wv,
            (ushort4*)xb, (ushort4*)wib, (float4*)pz, n4x, n4w);
    }

    // 2) h = x @ W_in^T + b_in   -> bf16 [N,H]   (reads xb, writes hb)
    dim3 gNH(NHID / 128, NTOK / 128);   // (8, 64)
    gemm_bt<1, false><<<gNH, 256, 0, stream>>>(
        xb, wib, hb, b_in, nullptr, 1.0f, NTOK, NHID, NHID, NHID, NHID);

    // 3) [q|k|v] = h @ [Wq;Wk;Wv]^T -> qkv [N, 3072]  (single fused GEMM)
    dim3 gQKV(3 * NHID / 128, NTOK / 128);  // (24, 64)
    gemm_bt<1, false><<<gQKV, 256, 0, stream>>>(
        hb, wqkvb, qkv, nullptr, nullptr, 1.0f, NTOK, 3 * NHID, NHID, NHID, NHID);

    // 4) P = exp(0.25 * q @ k^T - 64) -> bf16 [N,N]; fused z_j = sum_i P[i,j]
    //    q = qkv[:,0:1024] (lda=3072), k = qkv[:,1024:2048] (ldb=3072)
    dim3 gS(NTOK / 128, NTOK / 128);    // (64, 64)
    gemm_bt<2, false><<<gS, 256, 0, stream>>>(
        qkv, qkv + NHID, Pb, nullptr, pz, 0.25f, NTOK, NTOK, NHID,
        3 * NHID, 3 * NHID);

    // 5) vtb[h][j] = v[j][h] / z_j   (v = qkv[:,2048:3072], stride 3072)
    dim3 gT(NTOK / 64, NHID / 64);      // (128, 16)
    transpose_scale<<<gT, 256, 0, stream>>>(qkv + 2 * NHID, pz, vtb);

    // 6) out = P @ v'^T -> bf16 [N,H]  (outb aliases dead q region)
    //    SWAP grid: row-blocks dispatch-fastest -> A (P) L3-resident re-read
    dim3 gO(NTOK / 128, NHID / 128);    // (64, 8) with SWAP mapping
    gemm_bt<1, true><<<gO, 256, 0, stream>>>(
        Pb, vtb, outb, nullptr, nullptr, 1.0f, NTOK, NHID, NTOK, NTOK, NTOK);

    // 7) d_out[i] = sum_h logcosh(outb[i,h])
    logcosh_rowsum<<<NTOK, 256, 0, stream>>>((const ushort4*)outb, out);
}